// Round 13
// baseline (251.779 us; speedup 1.0000x reference)
//
#include <hip/hip_runtime.h>
#include <hip/hip_bf16.h>

// GATConv, N=8192, F_in=F_out=128, dense 0/1 adjacency (int32).
// Rank-1 logits: e_ij = LeakyReLU(es_i + ed_j), es = X@(W@a_src), ed = X@(W@a_dst).
// exp safe in f32 -> additive softmax partials, no max-shift.
//
// R13:
//  kF: fused [k1-role blocks 0..255 | kA-role blocks 256..4351]. k1 (X@W etc,
//      ~10us) hides under the mandatory 256MB A->bits stream (~50us).
//  k2: register-reuse masked GEMM. Wave = 32 rows (R=2 rgs) x 64 cols (C=4)
//      x 1024-j slice: each B-frag feeds 2 MFMAs, halving L2 B-traffic vs R12
//      (1GB -> 524MB) and ed dup x8 -> x2. 1-step-deep phase-reg prefetch,
//      no LDS/barriers/atomics, disjoint stores into 8 jo-partials.
//  k3: sum 8 partials + den, divide, ELU.

typedef __bf16 bf16_t;
typedef bf16_t bf16x8 __attribute__((ext_vector_type(8)));
typedef float  f32x4  __attribute__((ext_vector_type(4)));
typedef int    i32x4  __attribute__((ext_vector_type(4)));

#define NN 8192
#define DD 128
#define NSLICE 8

// ---- kF: fused k1 (blocks 0..255) + kA pack (blocks 256..4351) ----
__global__ __launch_bounds__(512) void kF_pre(const float* __restrict__ X,
                                              const float* __restrict__ W,
                                              const float* __restrict__ a_src,
                                              const float* __restrict__ a_dst,
                                              const int* __restrict__ A,
                                              unsigned* __restrict__ bits,
                                              float* __restrict__ es,
                                              float* __restrict__ edv,
                                              bf16_t* __restrict__ VB) {
  __shared__ float Wl[DD * DD];
  __shared__ bf16_t Tl[DD][40];
  const int t = threadIdx.x;

  if (blockIdx.x >= 256) {
    // ---- kA role: pack 512 words of adjacency ----
    const int w = (blockIdx.x - 256) * 512 + t;
    const i32x4* p = (const i32x4*)(A + (size_t)w * 32);
    i32x4 v[8];
    #pragma unroll
    for (int q = 0; q < 8; ++q) v[q] = p[q];
    unsigned m = 0;
    #pragma unroll
    for (int q = 0; q < 8; ++q) {
      #pragma unroll
      for (int e = 0; e < 4; ++e) m |= ((unsigned)v[q][e]) << (q * 4 + e);  // A is 0/1
    }
    const int row = w >> 8;
    const int c0 = (w & 255) << 5;
    if (row >= c0 && row < c0 + 32) m |= 1u << (row - c0);  // self-loop
    bits[w] = m;
    return;
  }

  // ---- k1 role ----
  const int rb = blockIdx.x << 5;

  if (t < 256) {
    const int k = t & 127;
    const float* av = (t < 128) ? a_src : a_dst;
    const f32x4* wrow = (const f32x4*)(W + k * DD);
    float s = 0.f;
    #pragma unroll
    for (int c4 = 0; c4 < 32; ++c4) {
      const f32x4 wv = wrow[c4];
      const f32x4 avv = *(const f32x4*)(av + c4 * 4);
      s += wv[0] * avv[0] + wv[1] * avv[1] + wv[2] * avv[2] + wv[3] * avv[3];
    }
    Wl[t] = s;
  }
  if (t < 64) Wl[256 + t] = 0.f;
  __syncthreads();

  {
    const int r = t >> 4, part = t & 15;
    const f32x4* xrow = (const f32x4*)(X + (size_t)(rb + r) * DD + part * 8);
    float s = 0.f, d = 0.f;
    #pragma unroll
    for (int q = 0; q < 2; ++q) {
      const f32x4 xv = xrow[q];
      const f32x4 sv = *(const f32x4*)(Wl + part * 8 + q * 4);
      const f32x4 dv = *(const f32x4*)(Wl + 128 + part * 8 + q * 4);
      s += xv[0] * sv[0] + xv[1] * sv[1] + xv[2] * sv[2] + xv[3] * sv[3];
      d += xv[0] * dv[0] + xv[1] * dv[1] + xv[2] * dv[2] + xv[3] * dv[3];
    }
    atomicAdd(&Wl[256 + r], s);
    atomicAdd(&Wl[288 + r], d);
  }
  __syncthreads();
  if (t < 32) {
    es[rb + t] = Wl[256 + t];
  } else if (t < 64) {
    edv[rb + t - 32] = Wl[288 + t - 32];
  }
  __syncthreads();

  for (int idx = t; idx < DD * DD; idx += 512) Wl[idx] = W[idx];
  __syncthreads();

  const int c = t & 127;
  const int r0 = t >> 7;
  for (int rr = 0; rr < 8; ++rr) {
    const int r = (rr << 2) + r0;
    const f32x4* xrow = (const f32x4*)(X + (size_t)(rb + r) * DD);
    float acc = 0.f;
    #pragma unroll
    for (int k4 = 0; k4 < 32; ++k4) {
      const f32x4 xv = xrow[k4];
      acc += xv[0] * Wl[(k4 * 4 + 0) * DD + c] + xv[1] * Wl[(k4 * 4 + 1) * DD + c] +
             xv[2] * Wl[(k4 * 4 + 2) * DD + c] + xv[3] * Wl[(k4 * 4 + 3) * DD + c];
    }
    Tl[c][r] = (bf16_t)acc;
  }
  __syncthreads();

  // VB[((jb*8 + cb)*64 + lane)*8 + e] = H[jb*32 + (lane>>4)*8 + e][cb*16 + (lane&15)]
  {
    const int cb = t >> 6;
    const int lane = t & 63;
    const int col = (cb << 4) + (lane & 15);
    const int rloc = (lane >> 4) << 3;
    const bf16x8 u = *(const bf16x8*)&Tl[col][rloc];
    *(bf16x8*)(VB + ((((size_t)(rb >> 5) << 3) + cb) * 64 + lane) * 8) = u;
  }
}

// ---- K2: register-reuse masked GEMM. 512 blocks x 512 thr (8 waves). ----
// Grid = 64 rowtiles (128 rows) x 8 jo (1024 j). Wave (rh 0..3, ch 0..1):
// rows rt*128 + rh*32 + rg*16 + l16 (rg=0,1), cols ch*64 + cf*16 + l16,
// 32 steps of 32 j. Per step: 2 bits + 2 ed + 4 B loads (1-deep phase regs),
// 16 exp, 8 MFMA (each B-frag reused by 2 A-frags). No LDS/barriers/atomics.
__global__ __launch_bounds__(512, 4) void k2_gat(const unsigned* __restrict__ bits,
                                                 const float* __restrict__ es,
                                                 const float* __restrict__ edv,
                                                 const bf16_t* __restrict__ VB,
                                                 float* __restrict__ num,
                                                 float* __restrict__ denP) {
  const int t = threadIdx.x;
  const int lane = t & 63, wave = t >> 6;
  const int l16 = lane & 15, lk = lane >> 4;
  const int rh = wave >> 1, ch = wave & 1;
  const int rt = blockIdx.x >> 3;
  const int jo = blockIdx.x & 7;
  const int jo0 = jo << 10;

  const int row0 = (rt << 7) + (rh << 5) + l16;  // rg=0 row
  const float es0 = es[row0];
  const float es1 = es[row0 + 16];

  const unsigned* pB0 = bits + (size_t)row0 * 256 + (jo << 5);         // +s per step
  const unsigned* pB1 = bits + (size_t)(row0 + 16) * 256 + (jo << 5);
  const float* ped = edv + jo0 + (lk << 3);                             // +32*s
  const bf16_t* pV = VB + (((size_t)(jo << 5) << 3) + (ch << 2)) * 512 + lane * 8;
  // step stride 4096 elems, cf stride 512 elems

  f32x4 acc0[4], acc1[4];
  #pragma unroll
  for (int cf = 0; cf < 4; ++cf) {
    acc0[cf] = f32x4{0.f, 0.f, 0.f, 0.f};
    acc1[cf] = f32x4{0.f, 0.f, 0.f, 0.f};
  }
  float dsum0 = 0.f, dsum1 = 0.f;

  // two named phase-register sets (2-step rotation)
  unsigned bwA0, bwA1, bwB0, bwB1;
  f32x4 eAA, eAB, eBA, eBB;
  bf16x8 vA0, vA1, vA2, vA3, vB0, vB1, vB2, vB3;

  bwA0 = pB0[0]; bwA1 = pB1[0];
  eAA = *(const f32x4*)ped; eAB = *(const f32x4*)(ped + 4);
  vA0 = *(const bf16x8*)(pV);
  vA1 = *(const bf16x8*)(pV + 512);
  vA2 = *(const bf16x8*)(pV + 1024);
  vA3 = *(const bf16x8*)(pV + 1536);
  bwB0 = pB0[1]; bwB1 = pB1[1];
  eBA = *(const f32x4*)(ped + 32); eBB = *(const f32x4*)(ped + 36);
  vB0 = *(const bf16x8*)(pV + 4096);
  vB1 = *(const bf16x8*)(pV + 4096 + 512);
  vB2 = *(const bf16x8*)(pV + 4096 + 1024);
  vB3 = *(const bf16x8*)(pV + 4096 + 1536);

  auto step = [&](int s, unsigned& bw0, unsigned& bw1, f32x4& eA, f32x4& eB, bf16x8& w0,
                  bf16x8& w1, bf16x8& w2, bf16x8& w3) {
    const unsigned m0 = bw0 >> (lk << 3);
    const unsigned m1 = bw1 >> (lk << 3);
    bf16x8 pa0, pa1;
    float p0s = 0.f, p1s = 0.f;
    #pragma unroll
    for (int e = 0; e < 8; ++e) {
      const float edq = (e < 4) ? eA[e] : eB[e - 4];
      float x0 = es0 + edq;
      x0 = fmaxf(x0, 0.2f * x0);
      float x1 = es1 + edq;
      x1 = fmaxf(x1, 0.2f * x1);
      const float p0 = ((m0 >> e) & 1u) ? __expf(x0) : 0.f;
      const float p1 = ((m1 >> e) & 1u) ? __expf(x1) : 0.f;
      p0s += p0;
      p1s += p1;
      pa0[e] = (bf16_t)p0;
      pa1[e] = (bf16_t)p1;
    }
    dsum0 += p0s;
    dsum1 += p1s;
    // 8 MFMA: each B-frag reused by both row-groups
    acc0[0] = __builtin_amdgcn_mfma_f32_16x16x32_bf16(pa0, w0, acc0[0], 0, 0, 0);
    acc1[0] = __builtin_amdgcn_mfma_f32_16x16x32_bf16(pa1, w0, acc1[0], 0, 0, 0);
    acc0[1] = __builtin_amdgcn_mfma_f32_16x16x32_bf16(pa0, w1, acc0[1], 0, 0, 0);
    acc1[1] = __builtin_amdgcn_mfma_f32_16x16x32_bf16(pa1, w1, acc1[1], 0, 0, 0);
    acc0[2] = __builtin_amdgcn_mfma_f32_16x16x32_bf16(pa0, w2, acc0[2], 0, 0, 0);
    acc1[2] = __builtin_amdgcn_mfma_f32_16x16x32_bf16(pa1, w2, acc1[2], 0, 0, 0);
    acc0[3] = __builtin_amdgcn_mfma_f32_16x16x32_bf16(pa0, w3, acc0[3], 0, 0, 0);
    acc1[3] = __builtin_amdgcn_mfma_f32_16x16x32_bf16(pa1, w3, acc1[3], 0, 0, 0);
    // prefetch step s+2 into the just-consumed phase registers
    if (s + 2 < 32) {
      const int o = (s + 2) << 5;
      bw0 = pB0[s + 2];
      bw1 = pB1[s + 2];
      eA = *(const f32x4*)(ped + o);
      eB = *(const f32x4*)(ped + o + 4);
      const bf16_t* pv = pV + (size_t)(s + 2) * 4096;
      w0 = *(const bf16x8*)(pv);
      w1 = *(const bf16x8*)(pv + 512);
      w2 = *(const bf16x8*)(pv + 1024);
      w3 = *(const bf16x8*)(pv + 1536);
    }
  };

  #pragma unroll 1
  for (int g = 0; g < 16; ++g) {
    step(2 * g, bwA0, bwA1, eAA, eAB, vA0, vA1, vA2, vA3);
    step(2 * g + 1, bwB0, bwB1, eBA, eBB, vB0, vB1, vB2, vB3);
  }

  // den: reduce over lk (4 lanes share a row); write once (ch==0)
  dsum0 += __shfl_xor(dsum0, 16, 64);
  dsum0 += __shfl_xor(dsum0, 32, 64);
  dsum1 += __shfl_xor(dsum1, 16, 64);
  dsum1 += __shfl_xor(dsum1, 32, 64);
  if (ch == 0 && lane < 16) {
    denP[(size_t)jo * NN + row0] = dsum0;
    denP[(size_t)jo * NN + row0 + 16] = dsum1;
  }

  // num: disjoint plain stores (C/D: row=(lane>>4)*4+reg, col=lane&15)
  float* nq = num + (size_t)jo * (NN * DD);
  #pragma unroll
  for (int cf = 0; cf < 4; ++cf) {
    const int col = (ch << 6) + (cf << 4) + l16;
    #pragma unroll
    for (int r = 0; r < 4; ++r) {
      const int rl = (rt << 7) + (rh << 5) + (lk << 2) + r;
      nq[(size_t)rl * DD + col] = acc0[cf][r];
      nq[(size_t)(rl + 16) * DD + col] = acc1[cf][r];
    }
  }
}

// ---- K3: out = elu( (sum_s num_s) / (sum_s den_s) ) ----
__global__ __launch_bounds__(256) void k3_fin(const float* __restrict__ num,
                                              const float* __restrict__ denP,
                                              float* __restrict__ out) {
  const int g = blockIdx.x * 256 + threadIdx.x;
  const size_t b = (size_t)g * 8;
  const int row = (int)(b >> 7);
  float den = 0.f;
  #pragma unroll
  for (int q = 0; q < NSLICE; ++q) den += denP[(size_t)q * NN + row];
  const float rd = 1.f / den;
  f32x4 s0 = {0.f, 0.f, 0.f, 0.f}, s1 = {0.f, 0.f, 0.f, 0.f};
  #pragma unroll
  for (int q = 0; q < NSLICE; ++q) {
    const float* nb = num + (size_t)q * (NN * DD);
    s0 += *(const f32x4*)(nb + b);
    s1 += *(const f32x4*)(nb + b + 4);
  }
  #pragma unroll
  for (int e = 0; e < 4; ++e) {
    float v = s0[e] * rd;
    s0[e] = v > 0.f ? v : (__expf(v) - 1.f);
    v = s1[e] * rd;
    s1[e] = v > 0.f ? v : (__expf(v) - 1.f);
  }
  *(f32x4*)(out + b) = s0;
  *(f32x4*)(out + b + 4) = s1;
}

extern "C" void kernel_launch(void* const* d_in, const int* in_sizes, int n_in,
                              void* d_out, int out_size, void* d_ws, size_t ws_size,
                              hipStream_t stream) {
  const float* X = (const float*)d_in[0];
  const int* A = (const int*)d_in[1];
  const float* W = (const float*)d_in[2];
  const float* a_src = (const float*)d_in[3];
  const float* a_dst = (const float*)d_in[4];
  float* out = (float*)d_out;

  char* w = (char*)d_ws;
  unsigned* bitsv = (unsigned*)(w + 0);  // 8 MB
  bf16_t* VB = (bf16_t*)(w + 8388608);   // 2 MB frag-major H
  float* es = (float*)(w + 10485760);    // 32 KB
  float* edv = (float*)(w + 10518528);   // 32 KB
  float* denP = (float*)(w + 10551296);  // 8 x 32 KB
  float* num = (float*)(w + 10813440);   // 8 x 4 MB (total ~43 MB)

  hipLaunchKernelGGL(kF_pre, dim3(256 + 4096), dim3(512), 0, stream, X, W, a_src,
                     a_dst, A, bitsv, es, edv, VB);
  hipLaunchKernelGGL(k2_gat, dim3(512), dim3(512), 0, stream, bitsv, es, edv, VB, num,
                     denP);
  hipLaunchKernelGGL(k3_fin, dim3(512), dim3(256), 0, stream, num, denP, out);
}

// Round 14
// 160.037 us; speedup vs baseline: 1.5733x; 1.5733x over previous
//
#include <hip/hip_runtime.h>
#include <hip/hip_bf16.h>

// GATConv, N=8192, F_in=F_out=128, dense 0/1 adjacency (int32).
// Rank-1 logits: e_ij = LeakyReLU(es_i + ed_j), es = X@(W@a_src), ed = X@(W@a_dst).
// exp safe in f32 -> additive softmax partials, no max-shift.
//
// R14: k2 produces FINAL output directly — no global partials (R13's 430MB
// write amplification + VB re-fetch made partials-based designs traffic-bound).
//  kF: fused [k1-role blocks 0..255 | kA-role 256..4351] (A->bits hides k1).
//  k2: 256 blocks x 8 waves; block = 32 rows x FULL j. Wave = 1024-j slice,
//      32 steps: [8 V-frag loads][bits/ed s+1 phase-reg prefetch][16 exp]
//      [16 MFMA, B-frag reused x2 rgs]. Epilogue: LDS atomic merge (16KB),
//      den shfl+LDS, ELU, one coalesced 4MB store. No k3.

typedef __bf16 bf16_t;
typedef bf16_t bf16x8 __attribute__((ext_vector_type(8)));
typedef float  f32x4  __attribute__((ext_vector_type(4)));
typedef int    i32x4  __attribute__((ext_vector_type(4)));

#define NN 8192
#define DD 128

// ---- kF: fused k1 (blocks 0..255) + kA pack (blocks 256..4351) ----
__global__ __launch_bounds__(512) void kF_pre(const float* __restrict__ X,
                                              const float* __restrict__ W,
                                              const float* __restrict__ a_src,
                                              const float* __restrict__ a_dst,
                                              const int* __restrict__ A,
                                              unsigned* __restrict__ bits,
                                              float* __restrict__ es,
                                              float* __restrict__ edv,
                                              bf16_t* __restrict__ VB) {
  __shared__ float Wl[DD * DD];
  __shared__ bf16_t Tl[DD][40];
  const int t = threadIdx.x;

  if (blockIdx.x >= 256) {
    // ---- kA role: pack 512 words of adjacency ----
    const int w = (blockIdx.x - 256) * 512 + t;
    const i32x4* p = (const i32x4*)(A + (size_t)w * 32);
    i32x4 v[8];
    #pragma unroll
    for (int q = 0; q < 8; ++q) v[q] = p[q];
    unsigned m = 0;
    #pragma unroll
    for (int q = 0; q < 8; ++q) {
      #pragma unroll
      for (int e = 0; e < 4; ++e) m |= ((unsigned)v[q][e]) << (q * 4 + e);  // A is 0/1
    }
    const int row = w >> 8;
    const int c0 = (w & 255) << 5;
    if (row >= c0 && row < c0 + 32) m |= 1u << (row - c0);  // self-loop
    bits[w] = m;
    return;
  }

  // ---- k1 role ----
  const int rb = blockIdx.x << 5;

  if (t < 256) {
    const int k = t & 127;
    const float* av = (t < 128) ? a_src : a_dst;
    const f32x4* wrow = (const f32x4*)(W + k * DD);
    float s = 0.f;
    #pragma unroll
    for (int c4 = 0; c4 < 32; ++c4) {
      const f32x4 wv = wrow[c4];
      const f32x4 avv = *(const f32x4*)(av + c4 * 4);
      s += wv[0] * avv[0] + wv[1] * avv[1] + wv[2] * avv[2] + wv[3] * avv[3];
    }
    Wl[t] = s;
  }
  if (t < 64) Wl[256 + t] = 0.f;
  __syncthreads();

  {
    const int r = t >> 4, part = t & 15;
    const f32x4* xrow = (const f32x4*)(X + (size_t)(rb + r) * DD + part * 8);
    float s = 0.f, d = 0.f;
    #pragma unroll
    for (int q = 0; q < 2; ++q) {
      const f32x4 xv = xrow[q];
      const f32x4 sv = *(const f32x4*)(Wl + part * 8 + q * 4);
      const f32x4 dv = *(const f32x4*)(Wl + 128 + part * 8 + q * 4);
      s += xv[0] * sv[0] + xv[1] * sv[1] + xv[2] * sv[2] + xv[3] * sv[3];
      d += xv[0] * dv[0] + xv[1] * dv[1] + xv[2] * dv[2] + xv[3] * dv[3];
    }
    atomicAdd(&Wl[256 + r], s);
    atomicAdd(&Wl[288 + r], d);
  }
  __syncthreads();
  if (t < 32) {
    es[rb + t] = Wl[256 + t];
  } else if (t < 64) {
    edv[rb + t - 32] = Wl[288 + t - 32];
  }
  __syncthreads();

  for (int idx = t; idx < DD * DD; idx += 512) Wl[idx] = W[idx];
  __syncthreads();

  const int c = t & 127;
  const int r0 = t >> 7;
  for (int rr = 0; rr < 8; ++rr) {
    const int r = (rr << 2) + r0;
    const f32x4* xrow = (const f32x4*)(X + (size_t)(rb + r) * DD);
    float acc = 0.f;
    #pragma unroll
    for (int k4 = 0; k4 < 32; ++k4) {
      const f32x4 xv = xrow[k4];
      acc += xv[0] * Wl[(k4 * 4 + 0) * DD + c] + xv[1] * Wl[(k4 * 4 + 1) * DD + c] +
             xv[2] * Wl[(k4 * 4 + 2) * DD + c] + xv[3] * Wl[(k4 * 4 + 3) * DD + c];
    }
    Tl[c][r] = (bf16_t)acc;
  }
  __syncthreads();

  // VB[((jb*8 + cb)*64 + lane)*8 + e] = H[jb*32 + (lane>>4)*8 + e][cb*16 + (lane&15)]
  {
    const int cb = t >> 6;
    const int lane = t & 63;
    const int col = (cb << 4) + (lane & 15);
    const int rloc = (lane >> 4) << 3;
    const bf16x8 u = *(const bf16x8*)&Tl[col][rloc];
    *(bf16x8*)(VB + ((((size_t)(rb >> 5) << 3) + cb) * 64 + lane) * 8) = u;
  }
}

// ---- K2: final-output masked GEMM. 256 blocks x 512 thr (8 waves). ----
// Block = rows rb..rb+32 (2 rgs of 16), full j. Wave ws: j-slice
// [ws*1024,(ws+1)*1024), 32 steps of 32 j. No global partials.
__global__ __launch_bounds__(512, 2) void k2_gat(const unsigned* __restrict__ bits,
                                                 const float* __restrict__ es,
                                                 const float* __restrict__ edv,
                                                 const bf16_t* __restrict__ VB,
                                                 float* __restrict__ out) {
  __shared__ float numL[32 * DD];  // 16 KB
  __shared__ float denL[32];
  const int t = threadIdx.x;
  const int lane = t & 63, ws = t >> 6;
  const int l16 = lane & 15, lk = lane >> 4;
  const int rb = blockIdx.x << 5;

  for (int idx = t; idx < 32 * DD; idx += 512) numL[idx] = 0.f;
  if (t < 32) denL[t] = 0.f;

  const int r0 = rb + l16;
  const int r1 = r0 + 16;
  const float es0 = es[r0];
  const float es1 = es[r1];

  const unsigned* pB0 = bits + (size_t)r0 * 256 + (ws << 5);  // word s per step
  const unsigned* pB1 = bits + (size_t)r1 * 256 + (ws << 5);
  const float* ped = edv + (ws << 10) + (lk << 3);            // +32 per step
  const bf16_t* pV = VB + ((size_t)(ws << 5) * 4096) + lane * 8;  // +4096/step, cb*512

  f32x4 acc0[8], acc1[8];
  #pragma unroll
  for (int cb = 0; cb < 8; ++cb) {
    acc0[cb] = f32x4{0.f, 0.f, 0.f, 0.f};
    acc1[cb] = f32x4{0.f, 0.f, 0.f, 0.f};
  }
  float dsum0 = 0.f, dsum1 = 0.f;

  // 2-phase bits/ed registers (1 step ahead)
  unsigned bA0 = pB0[0], bA1 = pB1[0], bB0, bB1;
  f32x4 eA0 = *(const f32x4*)ped, eA1 = *(const f32x4*)(ped + 4), eB0, eB1;

  auto step = [&](int s, unsigned& cb0, unsigned& cb1, f32x4& ce0, f32x4& ce1,
                  unsigned& nb0, unsigned& nb1, f32x4& ne0, f32x4& ne1) {
    // (1) V-frag loads for this step (latency hides under P-compute)
    const bf16_t* pv = pV + (size_t)s * 4096;
    bf16x8 vb[8];
    #pragma unroll
    for (int cb = 0; cb < 8; ++cb) vb[cb] = *(const bf16x8*)(pv + (cb << 9));
    // (2) prefetch bits/ed for step s+1 into the other phase
    if (s + 1 < 32) {
      nb0 = pB0[s + 1];
      nb1 = pB1[s + 1];
      const int o = (s + 1) << 5;
      ne0 = *(const f32x4*)(ped + o);
      ne1 = *(const f32x4*)(ped + o + 4);
    }
    // (3) P in-reg (self-loop pre-baked in bits)
    const unsigned m0 = cb0 >> (lk << 3);
    const unsigned m1 = cb1 >> (lk << 3);
    bf16x8 pa0, pa1;
    float p0s = 0.f, p1s = 0.f;
    #pragma unroll
    for (int e = 0; e < 8; ++e) {
      const float edq = (e < 4) ? ce0[e] : ce1[e - 4];
      float x0 = es0 + edq;
      x0 = fmaxf(x0, 0.2f * x0);
      float x1 = es1 + edq;
      x1 = fmaxf(x1, 0.2f * x1);
      const float p0 = ((m0 >> e) & 1u) ? __expf(x0) : 0.f;
      const float p1 = ((m1 >> e) & 1u) ? __expf(x1) : 0.f;
      p0s += p0;
      p1s += p1;
      pa0[e] = (bf16_t)p0;
      pa1[e] = (bf16_t)p1;
    }
    dsum0 += p0s;
    dsum1 += p1s;
    // (4) 16 MFMA (each B-frag reused by both row-groups)
    #pragma unroll
    for (int cb = 0; cb < 8; ++cb) {
      acc0[cb] = __builtin_amdgcn_mfma_f32_16x16x32_bf16(pa0, vb[cb], acc0[cb], 0, 0, 0);
      acc1[cb] = __builtin_amdgcn_mfma_f32_16x16x32_bf16(pa1, vb[cb], acc1[cb], 0, 0, 0);
    }
  };

  #pragma unroll 1
  for (int g = 0; g < 16; ++g) {
    step(2 * g, bA0, bA1, eA0, eA1, bB0, bB1, eB0, eB1);
    step(2 * g + 1, bB0, bB1, eB0, eB1, bA0, bA1, eA0, eA1);
  }

  // ---- epilogue: LDS merge across the 8 j-slice waves ----
  dsum0 += __shfl_xor(dsum0, 16, 64);
  dsum0 += __shfl_xor(dsum0, 32, 64);
  dsum1 += __shfl_xor(dsum1, 16, 64);
  dsum1 += __shfl_xor(dsum1, 32, 64);
  __syncthreads();  // numL/denL zero-init visible
  if (lane < 16) {
    atomicAdd(&denL[l16], dsum0);
    atomicAdd(&denL[16 + l16], dsum1);
  }
  #pragma unroll
  for (int cb = 0; cb < 8; ++cb) {
    #pragma unroll
    for (int r = 0; r < 4; ++r) {
      // C/D: row = (lane>>4)*4 + reg, col = lane&15 (validated layout)
      atomicAdd(&numL[((lk << 2) + r) * DD + (cb << 4) + l16], acc0[cb][r]);
      atomicAdd(&numL[(16 + (lk << 2) + r) * DD + (cb << 4) + l16], acc1[cb][r]);
    }
  }
  __syncthreads();

  // divide + ELU + coalesced store
  {
    const int row = t >> 4;
    const int c0 = (t & 15) << 3;
    const float rd = 1.f / denL[row];
    f32x4 o0, o1;
    #pragma unroll
    for (int q = 0; q < 4; ++q) {
      float v = numL[row * DD + c0 + q] * rd;
      o0[q] = v > 0.f ? v : (__expf(v) - 1.f);
      v = numL[row * DD + c0 + 4 + q] * rd;
      o1[q] = v > 0.f ? v : (__expf(v) - 1.f);
    }
    float* op = out + (size_t)(rb + row) * DD + c0;
    *(f32x4*)op = o0;
    *(f32x4*)(op + 4) = o1;
  }
}

extern "C" void kernel_launch(void* const* d_in, const int* in_sizes, int n_in,
                              void* d_out, int out_size, void* d_ws, size_t ws_size,
                              hipStream_t stream) {
  const float* X = (const float*)d_in[0];
  const int* A = (const int*)d_in[1];
  const float* W = (const float*)d_in[2];
  const float* a_src = (const float*)d_in[3];
  const float* a_dst = (const float*)d_in[4];
  float* out = (float*)d_out;

  char* w = (char*)d_ws;
  unsigned* bitsv = (unsigned*)(w + 0);  // 8 MB
  bf16_t* VB = (bf16_t*)(w + 8388608);   // 2 MB frag-major H
  float* es = (float*)(w + 10485760);    // 32 KB
  float* edv = (float*)(w + 10518528);   // 32 KB  (total ~10.1 MB)

  hipLaunchKernelGGL(kF_pre, dim3(256 + 4096), dim3(512), 0, stream, X, W, a_src,
                     a_dst, A, bitsv, es, edv, VB);
  hipLaunchKernelGGL(k2_gat, dim3(256), dim3(512), 0, stream, bitsv, es, edv, VB, out);
}

// Round 15
// 159.828 us; speedup vs baseline: 1.5753x; 1.0013x over previous
//
#include <hip/hip_runtime.h>
#include <hip/hip_bf16.h>

// GATConv, N=8192, F_in=F_out=128, dense 0/1 adjacency (int32).
// Rank-1 logits: e_ij = LeakyReLU(es_i + ed_j), es = X@(W@a_src), ed = X@(W@a_dst).
// exp safe in f32 -> additive softmax partials, no max-shift.
//
// R15: R14 kF (fused A->bits + k1, ~50us measured) unchanged. k2 rebuilt for
// latency: grid = 256 rowtiles x 2 col-halves = 512 blocks (2/CU -> 4 waves/
// SIMD), each block 32 rows x 64 cols x full j; per-wave 1024-j slice, 32
// steps. FULL 1-step-ahead register pipeline: VB(s+1), bits(s+1), ed(s+1)
// all issued during step s. P computed redundantly per col-half (cheap VALU)
// -> no cross-block coupling, VB L2 traffic unchanged (512MB). LDS merge,
// ELU, disjoint final stores. No k3, no global partials.

typedef __bf16 bf16_t;
typedef bf16_t bf16x8 __attribute__((ext_vector_type(8)));
typedef float  f32x4  __attribute__((ext_vector_type(4)));
typedef int    i32x4  __attribute__((ext_vector_type(4)));

#define NN 8192
#define DD 128

// ---- kF: fused k1 (blocks 0..255) + kA pack (blocks 256..4351) ----
__global__ __launch_bounds__(512) void kF_pre(const float* __restrict__ X,
                                              const float* __restrict__ W,
                                              const float* __restrict__ a_src,
                                              const float* __restrict__ a_dst,
                                              const int* __restrict__ A,
                                              unsigned* __restrict__ bits,
                                              float* __restrict__ es,
                                              float* __restrict__ edv,
                                              bf16_t* __restrict__ VB) {
  __shared__ float Wl[DD * DD];
  __shared__ bf16_t Tl[DD][40];
  const int t = threadIdx.x;

  if (blockIdx.x >= 256) {
    // ---- kA role: pack 512 words of adjacency ----
    const int w = (blockIdx.x - 256) * 512 + t;
    const i32x4* p = (const i32x4*)(A + (size_t)w * 32);
    i32x4 v[8];
    #pragma unroll
    for (int q = 0; q < 8; ++q) v[q] = p[q];
    unsigned m = 0;
    #pragma unroll
    for (int q = 0; q < 8; ++q) {
      #pragma unroll
      for (int e = 0; e < 4; ++e) m |= ((unsigned)v[q][e]) << (q * 4 + e);  // A is 0/1
    }
    const int row = w >> 8;
    const int c0 = (w & 255) << 5;
    if (row >= c0 && row < c0 + 32) m |= 1u << (row - c0);  // self-loop
    bits[w] = m;
    return;
  }

  // ---- k1 role ----
  const int rb = blockIdx.x << 5;

  if (t < 256) {
    const int k = t & 127;
    const float* av = (t < 128) ? a_src : a_dst;
    const f32x4* wrow = (const f32x4*)(W + k * DD);
    float s = 0.f;
    #pragma unroll
    for (int c4 = 0; c4 < 32; ++c4) {
      const f32x4 wv = wrow[c4];
      const f32x4 avv = *(const f32x4*)(av + c4 * 4);
      s += wv[0] * avv[0] + wv[1] * avv[1] + wv[2] * avv[2] + wv[3] * avv[3];
    }
    Wl[t] = s;
  }
  if (t < 64) Wl[256 + t] = 0.f;
  __syncthreads();

  {
    const int r = t >> 4, part = t & 15;
    const f32x4* xrow = (const f32x4*)(X + (size_t)(rb + r) * DD + part * 8);
    float s = 0.f, d = 0.f;
    #pragma unroll
    for (int q = 0; q < 2; ++q) {
      const f32x4 xv = xrow[q];
      const f32x4 sv = *(const f32x4*)(Wl + part * 8 + q * 4);
      const f32x4 dv = *(const f32x4*)(Wl + 128 + part * 8 + q * 4);
      s += xv[0] * sv[0] + xv[1] * sv[1] + xv[2] * sv[2] + xv[3] * sv[3];
      d += xv[0] * dv[0] + xv[1] * dv[1] + xv[2] * dv[2] + xv[3] * dv[3];
    }
    atomicAdd(&Wl[256 + r], s);
    atomicAdd(&Wl[288 + r], d);
  }
  __syncthreads();
  if (t < 32) {
    es[rb + t] = Wl[256 + t];
  } else if (t < 64) {
    edv[rb + t - 32] = Wl[288 + t - 32];
  }
  __syncthreads();

  for (int idx = t; idx < DD * DD; idx += 512) Wl[idx] = W[idx];
  __syncthreads();

  const int c = t & 127;
  const int r0 = t >> 7;
  for (int rr = 0; rr < 8; ++rr) {
    const int r = (rr << 2) + r0;
    const f32x4* xrow = (const f32x4*)(X + (size_t)(rb + r) * DD);
    float acc = 0.f;
    #pragma unroll
    for (int k4 = 0; k4 < 32; ++k4) {
      const f32x4 xv = xrow[k4];
      acc += xv[0] * Wl[(k4 * 4 + 0) * DD + c] + xv[1] * Wl[(k4 * 4 + 1) * DD + c] +
             xv[2] * Wl[(k4 * 4 + 2) * DD + c] + xv[3] * Wl[(k4 * 4 + 3) * DD + c];
    }
    Tl[c][r] = (bf16_t)acc;
  }
  __syncthreads();

  // VB[((jb*8 + cb)*64 + lane)*8 + e] = H[jb*32 + (lane>>4)*8 + e][cb*16 + (lane&15)]
  {
    const int cb = t >> 6;
    const int lane = t & 63;
    const int col = (cb << 4) + (lane & 15);
    const int rloc = (lane >> 4) << 3;
    const bf16x8 u = *(const bf16x8*)&Tl[col][rloc];
    *(bf16x8*)(VB + ((((size_t)(rb >> 5) << 3) + cb) * 64 + lane) * 8) = u;
  }
}

// ---- K2: final-output masked GEMM. 512 blocks (2/CU) x 512 thr (8 waves). ----
// Block = 32 rows x 64-col half x full j. Wave ws: j-slice [ws*1024,+1024),
// 32 steps of 32 j. 1-step-ahead register pipeline on VB/bits/ed.
__global__ __launch_bounds__(512, 4) void k2_gat(const unsigned* __restrict__ bits,
                                                 const float* __restrict__ es,
                                                 const float* __restrict__ edv,
                                                 const bf16_t* __restrict__ VB,
                                                 float* __restrict__ out) {
  __shared__ float numL[32 * 64];  // 8 KB (local col 0..63)
  __shared__ float denL[32];
  const int t = threadIdx.x;
  const int lane = t & 63, ws = t >> 6;
  const int l16 = lane & 15, lk = lane >> 4;
  const int rt = blockIdx.x >> 1;
  const int ch = blockIdx.x & 1;
  const int rb = rt << 5;

  for (int idx = t; idx < 32 * 64; idx += 512) numL[idx] = 0.f;
  if (t < 32) denL[t] = 0.f;

  const int r0 = rb + l16;
  const int r1 = r0 + 16;
  const float es0 = es[r0];
  const float es1 = es[r1];

  const unsigned* pB0 = bits + (size_t)r0 * 256 + (ws << 5);  // +s per step
  const unsigned* pB1 = bits + (size_t)r1 * 256 + (ws << 5);
  const float* ped = edv + (ws << 10) + (lk << 3);            // +32 per step
  // VB: [jb][cb][lane][8]; this block uses cb in [ch*4, ch*4+4)
  const bf16_t* pV = VB + (((size_t)(ws << 5) * 8 + (ch << 2)) * 64 + lane) * 8;
  // step stride 4096 elems; cb stride 512 elems

  f32x4 acc0[4], acc1[4];
  #pragma unroll
  for (int cf = 0; cf < 4; ++cf) {
    acc0[cf] = f32x4{0.f, 0.f, 0.f, 0.f};
    acc1[cf] = f32x4{0.f, 0.f, 0.f, 0.f};
  }
  float dsum0 = 0.f, dsum1 = 0.f;

  // phase registers (A = even steps, B = odd steps)
  unsigned bA0, bA1, bB0, bB1;
  f32x4 eA0, eA1, eB0, eB1;
  bf16x8 vA0, vA1, vA2, vA3, vB0, vB1, vB2, vB3;

  // prologue: load phase A for s=0
  bA0 = pB0[0];
  bA1 = pB1[0];
  eA0 = *(const f32x4*)ped;
  eA1 = *(const f32x4*)(ped + 4);
  vA0 = *(const bf16x8*)(pV);
  vA1 = *(const bf16x8*)(pV + 512);
  vA2 = *(const bf16x8*)(pV + 1024);
  vA3 = *(const bf16x8*)(pV + 1536);

  auto step = [&](int s, unsigned& cb0, unsigned& cb1, f32x4& ce0, f32x4& ce1,
                  bf16x8& cv0, bf16x8& cv1, bf16x8& cv2, bf16x8& cv3, unsigned& nb0,
                  unsigned& nb1, f32x4& ne0, f32x4& ne1, bf16x8& nv0, bf16x8& nv1,
                  bf16x8& nv2, bf16x8& nv3) {
    // (1) issue ALL of step s+1's loads into the other phase
    if (s + 1 < 32) {
      nb0 = pB0[s + 1];
      nb1 = pB1[s + 1];
      const int o = (s + 1) << 5;
      ne0 = *(const f32x4*)(ped + o);
      ne1 = *(const f32x4*)(ped + o + 4);
      const bf16_t* pv = pV + (size_t)(s + 1) * 4096;
      nv0 = *(const bf16x8*)(pv);
      nv1 = *(const bf16x8*)(pv + 512);
      nv2 = *(const bf16x8*)(pv + 1024);
      nv3 = *(const bf16x8*)(pv + 1536);
    }
    // (2) P in-reg from phase-s registers (self-loop pre-baked in bits)
    const unsigned m0 = cb0 >> (lk << 3);
    const unsigned m1 = cb1 >> (lk << 3);
    bf16x8 pa0, pa1;
    float p0s = 0.f, p1s = 0.f;
    #pragma unroll
    for (int e = 0; e < 8; ++e) {
      const float edq = (e < 4) ? ce0[e] : ce1[e - 4];
      float x0 = es0 + edq;
      x0 = fmaxf(x0, 0.2f * x0);
      float x1 = es1 + edq;
      x1 = fmaxf(x1, 0.2f * x1);
      const float p0 = ((m0 >> e) & 1u) ? __expf(x0) : 0.f;
      const float p1 = ((m1 >> e) & 1u) ? __expf(x1) : 0.f;
      p0s += p0;
      p1s += p1;
      pa0[e] = (bf16_t)p0;
      pa1[e] = (bf16_t)p1;
    }
    dsum0 += p0s;
    dsum1 += p1s;
    // (3) 8 MFMA on phase-s V fragments (loaded one full step ago)
    acc0[0] = __builtin_amdgcn_mfma_f32_16x16x32_bf16(pa0, cv0, acc0[0], 0, 0, 0);
    acc1[0] = __builtin_amdgcn_mfma_f32_16x16x32_bf16(pa1, cv0, acc1[0], 0, 0, 0);
    acc0[1] = __builtin_amdgcn_mfma_f32_16x16x32_bf16(pa0, cv1, acc0[1], 0, 0, 0);
    acc1[1] = __builtin_amdgcn_mfma_f32_16x16x32_bf16(pa1, cv1, acc1[1], 0, 0, 0);
    acc0[2] = __builtin_amdgcn_mfma_f32_16x16x32_bf16(pa0, cv2, acc0[2], 0, 0, 0);
    acc1[2] = __builtin_amdgcn_mfma_f32_16x16x32_bf16(pa1, cv2, acc1[2], 0, 0, 0);
    acc0[3] = __builtin_amdgcn_mfma_f32_16x16x32_bf16(pa0, cv3, acc0[3], 0, 0, 0);
    acc1[3] = __builtin_amdgcn_mfma_f32_16x16x32_bf16(pa1, cv3, acc1[3], 0, 0, 0);
  };

  #pragma unroll 1
  for (int g = 0; g < 16; ++g) {
    step(2 * g, bA0, bA1, eA0, eA1, vA0, vA1, vA2, vA3,
         bB0, bB1, eB0, eB1, vB0, vB1, vB2, vB3);
    step(2 * g + 1, bB0, bB1, eB0, eB1, vB0, vB1, vB2, vB3,
         bA0, bA1, eA0, eA1, vA0, vA1, vA2, vA3);
  }

  // ---- epilogue: LDS merge across the 8 j-slice waves ----
  dsum0 += __shfl_xor(dsum0, 16, 64);
  dsum0 += __shfl_xor(dsum0, 32, 64);
  dsum1 += __shfl_xor(dsum1, 16, 64);
  dsum1 += __shfl_xor(dsum1, 32, 64);
  __syncthreads();  // zero-init visible
  if (lane < 16) {
    atomicAdd(&denL[l16], dsum0);
    atomicAdd(&denL[16 + l16], dsum1);
  }
  #pragma unroll
  for (int cf = 0; cf < 4; ++cf) {
    #pragma unroll
    for (int r = 0; r < 4; ++r) {
      // C/D: row = (lane>>4)*4 + reg, col = lane&15 (validated layout)
      atomicAdd(&numL[((lk << 2) + r) * 64 + (cf << 4) + l16], acc0[cf][r]);
      atomicAdd(&numL[(16 + (lk << 2) + r) * 64 + (cf << 4) + l16], acc1[cf][r]);
    }
  }
  __syncthreads();

  // divide + ELU + disjoint coalesced store of this block's 64-col half
  {
    const int row = t >> 4;        // 0..31
    const int c0 = (t & 15) << 2;  // 0..60
    const float rd = 1.f / denL[row];
    f32x4 o;
    #pragma unroll
    for (int q = 0; q < 4; ++q) {
      float v = numL[row * 64 + c0 + q] * rd;
      o[q] = v > 0.f ? v : (__expf(v) - 1.f);
    }
    *(f32x4*)(out + (size_t)(rb + row) * DD + (ch << 6) + c0) = o;
  }
}

extern "C" void kernel_launch(void* const* d_in, const int* in_sizes, int n_in,
                              void* d_out, int out_size, void* d_ws, size_t ws_size,
                              hipStream_t stream) {
  const float* X = (const float*)d_in[0];
  const int* A = (const int*)d_in[1];
  const float* W = (const float*)d_in[2];
  const float* a_src = (const float*)d_in[3];
  const float* a_dst = (const float*)d_in[4];
  float* out = (float*)d_out;

  char* w = (char*)d_ws;
  unsigned* bitsv = (unsigned*)(w + 0);  // 8 MB
  bf16_t* VB = (bf16_t*)(w + 8388608);   // 2 MB frag-major H
  float* es = (float*)(w + 10485760);    // 32 KB
  float* edv = (float*)(w + 10518528);   // 32 KB  (total ~10.1 MB)

  hipLaunchKernelGGL(kF_pre, dim3(256 + 4096), dim3(512), 0, stream, X, W, a_src,
                     a_dst, A, bitsv, es, edv, VB);
  hipLaunchKernelGGL(k2_gat, dim3(512), dim3(512), 0, stream, bitsv, es, edv, VB, out);
}